// Round 6
// baseline (407.614 us; speedup 1.0000x reference)
//
#include <hip/hip_runtime.h>

// Morphological skeleton, 16 x 1024 x 1024 f32.
// skel = sum_{k=0..20} ( e_k - dilate3x3(e_{k+1}) ),  e_0 = x, e_{k+1} = erode3x3(e_k)
// (reduce_window SAME semantics: windows clamp at image borders).
//
// Register-resident vertical pipeline, zero LDS tile. 3 dispatches x G=7 fused
// erosion stages. One wave (64 lanes x float4) owns a 256-col band and sweeps
// RCH+16 rows. Per stage: 2-row register buffer (parity-swapped); erode =
// min3 vertical + DPP wave-shift horizontal; dilate of f_{s+1} reuses stage
// s+1's buffers; terms go into an 8-slot register RING, emitted as rows
// complete.
//
// Round-10 changes vs round 9 (324 us): instruction-count reduction at pinned
// ~50% single-wave duty (dependent-chain issue ceiling: 2-cy issue / ~4-cy
// dep latency; residency stuck at ~1.2 waves/SIMD in every config tested).
// Time tracks VALU count (R2: +35% VALU -> +38% time; R9: -DS latency ->
// -10% time). Cuts:
//  (a) acc FIFO shift (28 v_mov/step) deleted: 8-step-unrolled sweep loop
//      (t0 = 32k-8 === 0 mod 8 -> static phase), acc becomes a ring with
//      compile-time indices; stage 0 ASSIGNS (first writer of each row's
//      slot) so neither shifting nor zeroing is needed. Desk-proof: row r is
//      assigned by stage 0 at step r+2 (old occupant r-8 was emitted at step
//      r, dead), accumulated by stages 1..6 at steps r+3..r+8, emitted at
//      r+8 after stage 6's write in the same step.
//  (b) border-clamp cndmasks (4/stage) templated out per band: leftEdge only
//      exists in band 0, rightEdge only in band 4; bands 1-3 drop all 4,
//      bands 0/4 drop 2. Grid reordered (band = slow dim) for I-cache
//      locality across instantiations.
//
// Config: 4-wave WGs, RCH=32, EDGE folding, DPP shifts (all proven).
//
// Correctness invariants (desk-verified):
//  - ring slot for row r is r&7; stage s at step t touches row t-s-2 -> slot
//    (PHASE+6-s)&7, emit at step t reads row t-8 -> slot PHASE; stage 6
//    writes that slot earlier in the same step.
//  - interior test: topOK min at y0-17 >= 0 iff y0>=32; botOK max at y0+38 <
//    1024 iff y0<=960.
//  - y0 = 32k -> t0 = y0-8 divisible by 8 -> static phase & pf parity hold.
//  - synthetic erode values at OOB/warm-up rows are >= the true clamped
//    erosion => harmless in min chains; masked to -BIG in dilate maxes via
//    wave-uniform row conditionals (EDGE path).
//  - DPP bound-lane 0-fill lands only in border-masked lanes or unowned halo
//    columns (contamination <= 1 col/stage, absorbed by the 8-col shrink).
//  - halos exactly tight: 8 rows warm-up, 8 cols/side shrink; bands own
//    disjoint column ranges {[0,248),[248,488),[488,728),[728,968),
//    [968,1024)} so the skel read-modify-write never races.

static constexpr int W = 1024, H = 1024, NIMG = 16;
static constexpr int RCH = 32;           // output rows per wave
static constexpr int NSTEP = RCH + 16;   // sweep steps (8 warm-up + 8 drain)
static constexpr int WPB = 4;            // waves per workgroup
static constexpr float BIG = 3.0e38f;

__device__ __forceinline__ float min3f(float a, float b, float c) { return fminf(fminf(a, b), c); }
__device__ __forceinline__ float max3f(float a, float b, float c) { return fmaxf(fmaxf(a, b), c); }

// DPP whole-wave shifts (gfx9/CDNA-only modes; VALU pipe, no DS).
// wave_shr:1 = 0x138 -> lane i reads lane i-1 (left neighbor); lane 0 = 0.
// wave_shl:1 = 0x130 -> lane i reads lane i+1 (right neighbor); lane 63 = 0.
__device__ __forceinline__ float dpp_left(float v) {
    return __int_as_float(__builtin_amdgcn_mov_dpp(__float_as_int(v), 0x138, 0xF, 0xF, true));
}
__device__ __forceinline__ float dpp_right(float v) {
    return __int_as_float(__builtin_amdgcn_mov_dpp(__float_as_int(v), 0x130, 0xF, 0xF, true));
}

template<bool FIRST, bool WRITE_E, bool EDGE, bool LE, bool RE, int PHASE>
__device__ __forceinline__
void pipe_step(int t, int y0, int gx,
               bool leftEdge, bool rightEdge, bool lane_ok,
               const float* __restrict__ in, float* __restrict__ eo,
               float* __restrict__ sk,
               float4 (&OB)[7], float4 (&MB)[7], float4& OD, float4& MD,
               float4 (&acc)[8], float4 (&pf)[2], float4 (&skpf)[2])
{
    constexpr int PFI = PHASE & 1;

    // consume input row t (OOB rows are +BIG: erode identity; interior: always in-image)
    float4 cur;
    if (!EDGE || (unsigned)t < (unsigned)H) cur = pf[PFI];
    else                                    cur = make_float4(BIG, BIG, BIG, BIG);
    // prefetch input row t+2 into the slot just consumed
    {
        const int nr = t + 2;
        if ((!EDGE || (unsigned)nr < (unsigned)H) && nr <= y0 + RCH + 7)
            pf[PFI] = *(const float4*)&in[(size_t)nr * W + gx];
    }

#pragma unroll
    for (int s = 0; s < 7; ++s) {
        // invariant at entry: OB[s] = f_s(t-s-2), MB[s] = f_s(t-s-1),
        // cur = f_s(t-s) (produced this step by the previous stage / load).
        const float4 fOld = OB[s];
        const float4 fMid = MB[s];

        // ---- erode: en = f_{s+1}(t-s-1) ----
        float4 vm;
        vm.x = min3f(fOld.x, fMid.x, cur.x);
        vm.y = min3f(fOld.y, fMid.y, cur.y);
        vm.z = min3f(fOld.z, fMid.z, cur.z);
        vm.w = min3f(fOld.w, fMid.w, cur.w);
        float lft = dpp_left(vm.w);             // lane 0: 0-fill -> invalid col
        float rgt = dpp_right(vm.x);            // lane 63: 0-fill -> invalid col
        if (LE && leftEdge)  lft = BIG;         // true image border clamp
        if (RE && rightEdge) rgt = BIG;
        float4 en;
        en.x = min3f(lft,  vm.x, vm.y);
        en.y = min3f(vm.x, vm.y, vm.z);
        en.z = min3f(vm.y, vm.z, vm.w);
        en.w = min3f(vm.z, vm.w, rgt);

        OB[s] = cur;   // old-role slot receives newest f_s row (parity swap)

        // ---- dilate of f_{s+1} centered at row t-s-2 ----
        // gOld/gMid from stage s+1's buffers, read BEFORE their update in
        // iteration s+1 of this same step.
        float4 gOld, gMid;
        if (s < 6) { gOld = OB[s + 1]; gMid = MB[s + 1]; }  // f_{s+1}(t-s-3), (t-s-2)
        else       { gOld = OD;        gMid = MD;        }
        const bool topOK = !EDGE || ((t - s - 3) >= 0);   // row t-s-3 in-image?
        const bool botOK = !EDGE || ((t - s - 1) < H);    // row t-s-1 in-image?
        float4 vx;
        {
            float txx = topOK ? gOld.x : -BIG, bxx = botOK ? en.x : -BIG;
            float txy = topOK ? gOld.y : -BIG, bxy = botOK ? en.y : -BIG;
            float txz = topOK ? gOld.z : -BIG, bxz = botOK ? en.z : -BIG;
            float txw = topOK ? gOld.w : -BIG, bxw = botOK ? en.w : -BIG;
            vx.x = max3f(txx, gMid.x, bxx);
            vx.y = max3f(txy, gMid.y, bxy);
            vx.z = max3f(txz, gMid.z, bxz);
            vx.w = max3f(txw, gMid.w, bxw);
        }
        float dl = dpp_left(vx.w);
        float dr = dpp_right(vx.x);
        if (LE && leftEdge)  dl = -BIG;
        if (RE && rightEdge) dr = -BIG;
        float4 dn;
        dn.x = max3f(dl,   vx.x, vx.y);
        dn.y = max3f(vx.x, vx.y, vx.z);
        dn.z = max3f(vx.y, vx.z, vx.w);
        dn.w = max3f(vx.z, vx.w, dr);

        // term_s(t-s-2) = f_s(t-s-2) - dilate(f_{s+1})(t-s-2)
        // ring slot (t-s-2) & 7 = (PHASE+6-s) & 7; stage 0 ASSIGNS (first
        // writer of row t-2's slot; old occupant t-10 emitted at step t-2).
        constexpr int SL_BASE = 0;  // (readability)
        const int slot = (PHASE + 6 - s) & 7;   // compile-time after unroll
        (void)SL_BASE;
        if (s == 0) {
            acc[slot].x = fOld.x - dn.x;
            acc[slot].y = fOld.y - dn.y;
            acc[slot].z = fOld.z - dn.z;
            acc[slot].w = fOld.w - dn.w;
        } else {
            acc[slot].x += fOld.x - dn.x;
            acc[slot].y += fOld.y - dn.y;
            acc[slot].z += fOld.z - dn.z;
            acc[slot].w += fOld.w - dn.w;
        }

        if (s == 6) {
            if (WRITE_E) {
                const int er = t - 7;          // en = f_7(t-7)
                if (er >= y0 && er < y0 + RCH && lane_ok)
                    *(float4*)&eo[(size_t)er * W + gx] = en;
            }
            OD = en;
        }
        cur = en;   // becomes f_{s+1}(t-(s+1)) for the next stage
    }

    // ---- emit completed row t-8 (ring slot (t-8)&7 = PHASE; stage 6 wrote
    //      it earlier in this same step) ----
    if (t >= y0 + 8) {
        const int r = t - 8;
        float4 v = acc[PHASE];
        if (!FIRST) {
            const float4 o = skpf[PFI];        // skel row t-8, prefetched at step t-2
            v.x += o.x; v.y += o.y; v.z += o.z; v.w += o.w;
        }
        if (lane_ok)
            *(float4*)&sk[(size_t)r * W + gx] = v;
    }

    // ---- prefetch old skel row t-6 AFTER emission (consumed at step t+2,
    //      which shares this step's parity and thus this PFI slot) ----
    if (!FIRST) {
        const int pr = t - 6;
        if (pr >= y0 && pr < y0 + RCH)
            skpf[PFI] = *(const float4*)&sk[(size_t)pr * W + gx];
    }
}

template<bool FIRST, bool WRITE_E, bool EDGE, bool LE, bool RE>
__device__ __forceinline__
void sweep(int y0, int gx,
           bool leftEdge, bool rightEdge, bool lane_ok,
           const float* __restrict__ in, float* __restrict__ eo,
           float* __restrict__ sk)
{
    float4 B0[7], B1[7], D0, D1, acc[8], pf[2], skpf[2];
    const float4 big4 = make_float4(BIG, BIG, BIG, BIG);
    const float4 z4   = make_float4(0.f, 0.f, 0.f, 0.f);
#pragma unroll
    for (int s = 0; s < 7; ++s) { B0[s] = big4; B1[s] = big4; }
    D0 = big4; D1 = big4;
#pragma unroll
    for (int j = 0; j < 8; ++j) acc[j] = z4;
    pf[0] = big4; pf[1] = big4; skpf[0] = z4; skpf[1] = z4;

    // prefetch input rows t0, t0+1 (interior: always in-image)
    {
        const int r0 = y0 - 8, r1 = y0 - 7;
        if (!EDGE || r0 >= 0) pf[0] = *(const float4*)&in[(size_t)r0 * W + gx];
        if (!EDGE || r1 >= 0) pf[1] = *(const float4*)&in[(size_t)r1 * W + gx];
    }

    const int t0 = y0 - 8;   // 32k-8: divisible by 8 -> static phase mapping
#pragma unroll 1
    for (int t = t0; t < t0 + NSTEP; t += 8) {
        pipe_step<FIRST, WRITE_E, EDGE, LE, RE, 0>(t,     y0, gx, leftEdge, rightEdge, lane_ok,
                                                   in, eo, sk, B0, B1, D0, D1, acc, pf, skpf);
        pipe_step<FIRST, WRITE_E, EDGE, LE, RE, 1>(t + 1, y0, gx, leftEdge, rightEdge, lane_ok,
                                                   in, eo, sk, B1, B0, D1, D0, acc, pf, skpf);
        pipe_step<FIRST, WRITE_E, EDGE, LE, RE, 2>(t + 2, y0, gx, leftEdge, rightEdge, lane_ok,
                                                   in, eo, sk, B0, B1, D0, D1, acc, pf, skpf);
        pipe_step<FIRST, WRITE_E, EDGE, LE, RE, 3>(t + 3, y0, gx, leftEdge, rightEdge, lane_ok,
                                                   in, eo, sk, B1, B0, D1, D0, acc, pf, skpf);
        pipe_step<FIRST, WRITE_E, EDGE, LE, RE, 4>(t + 4, y0, gx, leftEdge, rightEdge, lane_ok,
                                                   in, eo, sk, B0, B1, D0, D1, acc, pf, skpf);
        pipe_step<FIRST, WRITE_E, EDGE, LE, RE, 5>(t + 5, y0, gx, leftEdge, rightEdge, lane_ok,
                                                   in, eo, sk, B1, B0, D1, D0, acc, pf, skpf);
        pipe_step<FIRST, WRITE_E, EDGE, LE, RE, 6>(t + 6, y0, gx, leftEdge, rightEdge, lane_ok,
                                                   in, eo, sk, B0, B1, D0, D1, acc, pf, skpf);
        pipe_step<FIRST, WRITE_E, EDGE, LE, RE, 7>(t + 7, y0, gx, leftEdge, rightEdge, lane_ok,
                                                   in, eo, sk, B1, B0, D1, D0, acc, pf, skpf);
    }
}

template<bool FIRST, bool WRITE_E>
__global__ __launch_bounds__(WPB * 64)
void skel_pipe(const float* __restrict__ ein, float* __restrict__ eout,
               float* __restrict__ skel)
{
    const int lane = threadIdx.x;          // 64 lanes; threadIdx.y selects the wave
    const int bx = blockIdx.y;             // band 0..4 (slow dim: I-cache locality)
    const int y0 = (blockIdx.x * WPB + (int)threadIdx.y) * RCH;  // private row chunk
    const int img = blockIdx.z;
    const int x0 = (bx == 4) ? 768 : bx * 240;   // last band starts at 1024-256
    const int gx = x0 + 4 * lane;                // gx max = 768 + 252 = 1020

    const size_t base = (size_t)img * (size_t)(W * H);
    const float* __restrict__ in = ein + base;
    float* __restrict__ eo = eout + base;
    float* __restrict__ sk = skel + base;

    const bool leftEdge  = (gx == 0);
    const bool rightEdge = (gx + 4 == W);
    // disjoint write ownership (bands overlap in compute, never in writes)
    const int own_lo = (bx == 0) ? 0 : ((bx == 4) ? 968 : x0 + 8);
    const int own_hi = (bx == 4) ? W : x0 + 248;
    const bool lane_ok = (gx >= own_lo) && (gx < own_hi);

    // interior chunk iff 32 <= y0 <= 960 (header proof)
    const bool edge_chunk = !(y0 >= 32 && y0 <= H - RCH - 32);

    if (bx == 0) {
        if (edge_chunk) sweep<FIRST, WRITE_E, true,  true,  false>(y0, gx, leftEdge, rightEdge, lane_ok, in, eo, sk);
        else            sweep<FIRST, WRITE_E, false, true,  false>(y0, gx, leftEdge, rightEdge, lane_ok, in, eo, sk);
    } else if (bx == 4) {
        if (edge_chunk) sweep<FIRST, WRITE_E, true,  false, true >(y0, gx, leftEdge, rightEdge, lane_ok, in, eo, sk);
        else            sweep<FIRST, WRITE_E, false, false, true >(y0, gx, leftEdge, rightEdge, lane_ok, in, eo, sk);
    } else {
        if (edge_chunk) sweep<FIRST, WRITE_E, true,  false, false>(y0, gx, leftEdge, rightEdge, lane_ok, in, eo, sk);
        else            sweep<FIRST, WRITE_E, false, false, false>(y0, gx, leftEdge, rightEdge, lane_ok, in, eo, sk);
    }
}

extern "C" void kernel_launch(void* const* d_in, const int* in_sizes, int n_in,
                              void* d_out, int out_size, void* d_ws, size_t ws_size,
                              hipStream_t stream)
{
    const float* x = (const float*)d_in[0];
    float* skel = (float*)d_out;
    const size_t n = (size_t)NIMG * W * H;

    float* e0 = (float*)d_ws;
    float* e1 = e0 + n;

    dim3 grid(H / (RCH * WPB), 5, NIMG);
    dim3 block(64, WPB);

    // steps 0-6: x -> e0 ; 7-13: e0 -> e1 ; 14-20: e1 -> (none)
    skel_pipe<true,  true ><<<grid, block, 0, stream>>>(x,  e0, skel);
    skel_pipe<false, true ><<<grid, block, 0, stream>>>(e0, e1, skel);
    skel_pipe<false, false><<<grid, block, 0, stream>>>(e1, e0, skel);
}

// Round 7
// 337.176 us; speedup vs baseline: 1.2089x; 1.2089x over previous
//
#include <hip/hip_runtime.h>

// Morphological skeleton, 16 x 1024 x 1024 f32.
// skel = sum_{k=0..20} ( e_k - dilate3x3(e_{k+1}) ),  e_0 = x, e_{k+1} = erode3x3(e_k)
// (reduce_window SAME semantics: windows clamp at image borders).
//
// Register-resident vertical pipeline, zero LDS tile. 3 dispatches x G=7 fused
// erosion stages. One wave (64 lanes x float4) owns a 256-col band and sweeps
// RCH+16 rows. Per stage: 2-row register buffer (parity-swapped); erode =
// min3 vertical + DPP wave-shift horizontal; dilate of f_{s+1} reuses stage
// s+1's buffers; terms go into an 8-deep register FIFO shifted once per
// 2-step pair.
//
// Round-11 = revert to round-9's 96us kernel (round-10's 8-phase acc ring
// blew VGPR 116->184, occupancy 14.6->7.6%, +22% time) plus the two
// register-neutral instruction cuts:
//  (a) LE/RE band templating: leftEdge only exists in band 0, rightEdge only
//      in band 4. Bands 1-3 (60% of waves) drop all 4 border cndmasks/stage,
//      bands 0/4 drop 2. No structural change.
//  (b) batched acc shift-by-2: keep the 2-step pair; step A writes slots 6-s,
//      emits acc[0] (IDENTICAL to round 9); step B writes slots 7-s, emits
//      acc[1]; one shift acc[j]=acc[j+2] (6 movs) per pair replaces two
//      7-mov shifts. Stage 0 ASSIGNS its slot (first writer of that row:
//      the old occupant was emitted 2 steps earlier and is dead), so no
//      zero-refill. Same 8 live slots -> zero VGPR delta.
//      Desk-proof: row r's slot is written by stage s at step r+s+2; under
//      the pair mapping r's slot index decreases by 2 per pair via the
//      shift, reaching slot 0 (r = tA-8) / slot 1 (r = tB-8) exactly at its
//      emit step; stage-6's write lands earlier in the same step.
//
// Config: 4-wave WGs, RCH=32, EDGE folding, DPP shifts (all proven).
//
// Correctness invariants (desk-verified):
//  - interior test: topOK min at y0-17 >= 0 iff y0>=32; botOK max at y0+38 <
//    1024 iff y0<=960.
//  - y0 = 32k -> t0 = y0-8 even -> pair/parity mapping of pf/skpf holds.
//  - synthetic erode values at OOB/warm-up rows are >= the true clamped
//    erosion => harmless in min chains; masked to -BIG in dilate maxes via
//    wave-uniform row conditionals (EDGE path).
//  - DPP bound-lane 0-fill lands only in border-masked lanes or unowned halo
//    columns (contamination <= 1 col/stage, absorbed by the 8-col shrink).
//  - band-edge folding: band 0 has no lane with gx+4==W (gx max 252), bands
//    1-3 have neither edge lane, band 4 has no gx==0 lane (gx min 768).
//  - halos exactly tight: 8 rows warm-up, 8 cols/side shrink; bands own
//    disjoint column ranges {[0,248),[248,488),[488,728),[728,968),
//    [968,1024)} so the skel read-modify-write never races.

static constexpr int W = 1024, H = 1024, NIMG = 16;
static constexpr int RCH = 32;           // output rows per wave
static constexpr int NSTEP = RCH + 16;   // sweep steps (8 warm-up + 8 drain)
static constexpr int WPB = 4;            // waves per workgroup
static constexpr float BIG = 3.0e38f;

__device__ __forceinline__ float min3f(float a, float b, float c) { return fminf(fminf(a, b), c); }
__device__ __forceinline__ float max3f(float a, float b, float c) { return fmaxf(fmaxf(a, b), c); }

// DPP whole-wave shifts (gfx9/CDNA-only modes; VALU pipe, no DS).
// wave_shr:1 = 0x138 -> lane i reads lane i-1 (left neighbor); lane 0 = 0.
// wave_shl:1 = 0x130 -> lane i reads lane i+1 (right neighbor); lane 63 = 0.
__device__ __forceinline__ float dpp_left(float v) {
    return __int_as_float(__builtin_amdgcn_mov_dpp(__float_as_int(v), 0x138, 0xF, 0xF, true));
}
__device__ __forceinline__ float dpp_right(float v) {
    return __int_as_float(__builtin_amdgcn_mov_dpp(__float_as_int(v), 0x130, 0xF, 0xF, true));
}

// SOFF: 0 for the first step of a pair (slots 6-s, emit acc[0]),
//       1 for the second (slots 7-s, emit acc[1]). Also the pf/skpf parity.
template<bool FIRST, bool WRITE_E, bool EDGE, bool LE, bool RE, int SOFF>
__device__ __forceinline__
void pipe_step(int t, int y0, int gx,
               bool leftEdge, bool rightEdge, bool lane_ok,
               const float* __restrict__ in, float* __restrict__ eo,
               float* __restrict__ sk,
               float4 (&OB)[7], float4 (&MB)[7], float4& OD, float4& MD,
               float4 (&acc)[8], float4 (&pf)[2], float4 (&skpf)[2])
{
    constexpr int PFI = SOFF;

    // consume input row t (OOB rows are +BIG: erode identity; interior: always in-image)
    float4 cur;
    if (!EDGE || (unsigned)t < (unsigned)H) cur = pf[PFI];
    else                                    cur = make_float4(BIG, BIG, BIG, BIG);
    // prefetch input row t+2 into the slot just consumed
    {
        const int nr = t + 2;
        if ((!EDGE || (unsigned)nr < (unsigned)H) && nr <= y0 + RCH + 7)
            pf[PFI] = *(const float4*)&in[(size_t)nr * W + gx];
    }

#pragma unroll
    for (int s = 0; s < 7; ++s) {
        // invariant at entry: OB[s] = f_s(t-s-2), MB[s] = f_s(t-s-1),
        // cur = f_s(t-s) (produced this step by the previous stage / load).
        const float4 fOld = OB[s];
        const float4 fMid = MB[s];

        // ---- erode: en = f_{s+1}(t-s-1) ----
        float4 vm;
        vm.x = min3f(fOld.x, fMid.x, cur.x);
        vm.y = min3f(fOld.y, fMid.y, cur.y);
        vm.z = min3f(fOld.z, fMid.z, cur.z);
        vm.w = min3f(fOld.w, fMid.w, cur.w);
        float lft = dpp_left(vm.w);             // lane 0: 0-fill -> invalid col
        float rgt = dpp_right(vm.x);            // lane 63: 0-fill -> invalid col
        if (LE && leftEdge)  lft = BIG;         // true image border clamp
        if (RE && rightEdge) rgt = BIG;
        float4 en;
        en.x = min3f(lft,  vm.x, vm.y);
        en.y = min3f(vm.x, vm.y, vm.z);
        en.z = min3f(vm.y, vm.z, vm.w);
        en.w = min3f(vm.z, vm.w, rgt);

        OB[s] = cur;   // old-role slot receives newest f_s row (parity swap)

        // ---- dilate of f_{s+1} centered at row t-s-2 ----
        // gOld/gMid from stage s+1's buffers, read BEFORE their update in
        // iteration s+1 of this same step.
        float4 gOld, gMid;
        if (s < 6) { gOld = OB[s + 1]; gMid = MB[s + 1]; }  // f_{s+1}(t-s-3), (t-s-2)
        else       { gOld = OD;        gMid = MD;        }
        const bool topOK = !EDGE || ((t - s - 3) >= 0);   // row t-s-3 in-image?
        const bool botOK = !EDGE || ((t - s - 1) < H);    // row t-s-1 in-image?
        float4 vx;
        {
            float txx = topOK ? gOld.x : -BIG, bxx = botOK ? en.x : -BIG;
            float txy = topOK ? gOld.y : -BIG, bxy = botOK ? en.y : -BIG;
            float txz = topOK ? gOld.z : -BIG, bxz = botOK ? en.z : -BIG;
            float txw = topOK ? gOld.w : -BIG, bxw = botOK ? en.w : -BIG;
            vx.x = max3f(txx, gMid.x, bxx);
            vx.y = max3f(txy, gMid.y, bxy);
            vx.z = max3f(txz, gMid.z, bxz);
            vx.w = max3f(txw, gMid.w, bxw);
        }
        float dl = dpp_left(vx.w);
        float dr = dpp_right(vx.x);
        if (LE && leftEdge)  dl = -BIG;
        if (RE && rightEdge) dr = -BIG;
        float4 dn;
        dn.x = max3f(dl,   vx.x, vx.y);
        dn.y = max3f(vx.x, vx.y, vx.z);
        dn.z = max3f(vx.y, vx.z, vx.w);
        dn.w = max3f(vx.z, vx.w, dr);

        // term_s(t-s-2) = f_s(t-s-2) - dilate(f_{s+1})(t-s-2)
        // slot SOFF+6-s (compile-time). Stage 0 ASSIGNS: first writer of row
        // t-2's slot (previous occupant emitted 2 steps ago, dead).
        constexpr int base = SOFF + 6;
        const int slot = base - s;
        if (s == 0) {
            acc[slot].x = fOld.x - dn.x;
            acc[slot].y = fOld.y - dn.y;
            acc[slot].z = fOld.z - dn.z;
            acc[slot].w = fOld.w - dn.w;
        } else {
            acc[slot].x += fOld.x - dn.x;
            acc[slot].y += fOld.y - dn.y;
            acc[slot].z += fOld.z - dn.z;
            acc[slot].w += fOld.w - dn.w;
        }

        if (s == 6) {
            if (WRITE_E) {
                const int er = t - 7;          // en = f_7(t-7)
                if (er >= y0 && er < y0 + RCH && lane_ok)
                    *(float4*)&eo[(size_t)er * W + gx] = en;
            }
            OD = en;
        }
        cur = en;   // becomes f_{s+1}(t-(s+1)) for the next stage
    }

    // ---- emit completed row t-8 (slot SOFF; stage 6 wrote it this step) ----
    if (t >= y0 + 8) {
        const int r = t - 8;
        float4 v = acc[SOFF];
        if (!FIRST) {
            const float4 o = skpf[PFI];        // skel row t-8, prefetched at step t-2
            v.x += o.x; v.y += o.y; v.z += o.z; v.w += o.w;
        }
        if (lane_ok)
            *(float4*)&sk[(size_t)r * W + gx] = v;
    }

    // ---- prefetch old skel row t-6 AFTER emission (consumed at step t+2,
    //      which shares this step's parity and thus this PFI slot) ----
    if (!FIRST) {
        const int pr = t - 6;
        if (pr >= y0 && pr < y0 + RCH)
            skpf[PFI] = *(const float4*)&sk[(size_t)pr * W + gx];
    }
}

template<bool FIRST, bool WRITE_E, bool EDGE, bool LE, bool RE>
__device__ __forceinline__
void sweep(int y0, int gx,
           bool leftEdge, bool rightEdge, bool lane_ok,
           const float* __restrict__ in, float* __restrict__ eo,
           float* __restrict__ sk)
{
    float4 B0[7], B1[7], D0, D1, acc[8], pf[2], skpf[2];
    const float4 big4 = make_float4(BIG, BIG, BIG, BIG);
    const float4 z4   = make_float4(0.f, 0.f, 0.f, 0.f);
#pragma unroll
    for (int s = 0; s < 7; ++s) { B0[s] = big4; B1[s] = big4; }
    D0 = big4; D1 = big4;
#pragma unroll
    for (int j = 0; j < 8; ++j) acc[j] = z4;   // safety only; stage-0 assigns
    pf[0] = big4; pf[1] = big4; skpf[0] = z4; skpf[1] = z4;

    // prefetch input rows t0, t0+1 (interior: always in-image)
    {
        const int r0 = y0 - 8, r1 = y0 - 7;
        if (!EDGE || r0 >= 0) pf[0] = *(const float4*)&in[(size_t)r0 * W + gx];
        if (!EDGE || r1 >= 0) pf[1] = *(const float4*)&in[(size_t)r1 * W + gx];
    }

    const int t0 = y0 - 8;   // even (y0 multiple of 32) -> pair mapping holds
#pragma unroll 1
    for (int t = t0; t < t0 + NSTEP; t += 2) {
        pipe_step<FIRST, WRITE_E, EDGE, LE, RE, 0>(t,     y0, gx, leftEdge, rightEdge, lane_ok,
                                                   in, eo, sk, B0, B1, D0, D1, acc, pf, skpf);
        pipe_step<FIRST, WRITE_E, EDGE, LE, RE, 1>(t + 1, y0, gx, leftEdge, rightEdge, lane_ok,
                                                   in, eo, sk, B1, B0, D1, D0, acc, pf, skpf);
        // one FIFO shift per pair (rows tA-6..tA-1: slots 2..7 -> 0..5)
#pragma unroll
        for (int j = 0; j < 6; ++j) acc[j] = acc[j + 2];
    }
}

template<bool FIRST, bool WRITE_E>
__global__ __launch_bounds__(WPB * 64)
void skel_pipe(const float* __restrict__ ein, float* __restrict__ eout,
               float* __restrict__ skel)
{
    const int lane = threadIdx.x;          // 64 lanes; threadIdx.y selects the wave
    const int bx = blockIdx.x;             // band 0..4
    const int y0 = (blockIdx.y * WPB + (int)threadIdx.y) * RCH;  // private row chunk
    const int img = blockIdx.z;
    const int x0 = (bx == 4) ? 768 : bx * 240;   // last band starts at 1024-256
    const int gx = x0 + 4 * lane;                // gx max = 768 + 252 = 1020

    const size_t base = (size_t)img * (size_t)(W * H);
    const float* __restrict__ in = ein + base;
    float* __restrict__ eo = eout + base;
    float* __restrict__ sk = skel + base;

    const bool leftEdge  = (gx == 0);
    const bool rightEdge = (gx + 4 == W);
    // disjoint write ownership (bands overlap in compute, never in writes)
    const int own_lo = (bx == 0) ? 0 : ((bx == 4) ? 968 : x0 + 8);
    const int own_hi = (bx == 4) ? W : x0 + 248;
    const bool lane_ok = (gx >= own_lo) && (gx < own_hi);

    // interior chunk iff 32 <= y0 <= 960 (header proof)
    const bool edge_chunk = !(y0 >= 32 && y0 <= H - RCH - 32);

    if (bx == 0) {
        if (edge_chunk) sweep<FIRST, WRITE_E, true,  true,  false>(y0, gx, leftEdge, rightEdge, lane_ok, in, eo, sk);
        else            sweep<FIRST, WRITE_E, false, true,  false>(y0, gx, leftEdge, rightEdge, lane_ok, in, eo, sk);
    } else if (bx == 4) {
        if (edge_chunk) sweep<FIRST, WRITE_E, true,  false, true >(y0, gx, leftEdge, rightEdge, lane_ok, in, eo, sk);
        else            sweep<FIRST, WRITE_E, false, false, true >(y0, gx, leftEdge, rightEdge, lane_ok, in, eo, sk);
    } else {
        if (edge_chunk) sweep<FIRST, WRITE_E, true,  false, false>(y0, gx, leftEdge, rightEdge, lane_ok, in, eo, sk);
        else            sweep<FIRST, WRITE_E, false, false, false>(y0, gx, leftEdge, rightEdge, lane_ok, in, eo, sk);
    }
}

extern "C" void kernel_launch(void* const* d_in, const int* in_sizes, int n_in,
                              void* d_out, int out_size, void* d_ws, size_t ws_size,
                              hipStream_t stream)
{
    const float* x = (const float*)d_in[0];
    float* skel = (float*)d_out;
    const size_t n = (size_t)NIMG * W * H;

    float* e0 = (float*)d_ws;
    float* e1 = e0 + n;

    dim3 grid(5, H / (RCH * WPB), NIMG);
    dim3 block(64, WPB);

    // steps 0-6: x -> e0 ; 7-13: e0 -> e1 ; 14-20: e1 -> (none)
    skel_pipe<true,  true ><<<grid, block, 0, stream>>>(x,  e0, skel);
    skel_pipe<false, true ><<<grid, block, 0, stream>>>(e0, e1, skel);
    skel_pipe<false, false><<<grid, block, 0, stream>>>(e1, e0, skel);
}